// Round 18
// baseline (174.617 us; speedup 1.0000x reference)
//
#include <hip/hip_runtime.h>
#include <hip/hip_bf16.h>

typedef float f32x4  __attribute__((ext_vector_type(4)));
typedef int   v8i    __attribute__((ext_vector_type(8)));
typedef unsigned short u16;
typedef unsigned char  u8;

#define B_ 4
#define C_ 512
#define H_ 128
#define W_ 128
#define NO_ 640   // 64 q + 64 k + 512 v output channels

__device__ __forceinline__ u16 f2bf(float f) {
    __hip_bfloat16 h = __float2bfloat16(f);
    union { __hip_bfloat16 h; u16 u; } cv; cv.h = h; return cv.u;
}
// fp8 e4m3 (OCP) pack: two floats -> low 2 bytes of result
__device__ __forceinline__ unsigned f2fp8x2(float a, float b) {
    return (unsigned)__builtin_amdgcn_cvt_pk_fp8_f32(a, b, 0, false);
}
__device__ __forceinline__ u8 f2fp8(float f) {
    return (u8)(f2fp8x2(f, 0.f) & 0xFF);
}
// branchless e4m3fn -> f32 decode (no builtin dependency)
__device__ __forceinline__ float fp82f(unsigned b) {
    const unsigned s = (b >> 7) & 1u, e = (b >> 3) & 15u, m = b & 7u;
    union { unsigned u; float f; } c;
    c.u = (s << 31) | ((e + 120u) << 23) | (m << 20);            // normal
    const float fs = (s ? -1.f : 1.f) * (float)m * 0.001953125f; // subnormal: m*2^-9
    return e ? c.f : fs;
}

// async global->LDS, 16B per lane; LDS dest must be wave_base + lane*16
__device__ __forceinline__ void gld16(const void* g, void* l) {
    __builtin_amdgcn_global_load_lds(
        (const __attribute__((address_space(1))) void*)g,
        (__attribute__((address_space(3))) void*)l, 16, 0, 0);
}

// ---------------------------------------------------------------- K0: weights -> fp8
__global__ __launch_bounds__(256) void k_convw(const float* __restrict__ Wq, const float* __restrict__ bq,
                                               const float* __restrict__ Wk, const float* __restrict__ bk,
                                               const float* __restrict__ Wv, const float* __restrict__ bv,
                                               u8* __restrict__ Wcat, float* __restrict__ bcat) {
    const int idx = blockIdx.x * 256 + threadIdx.x;
    if (idx < NO_ * C_) {
        const int o = idx >> 9, c = idx & 511;
        float v;
        if (o < 64)       v = Wq[o * C_ + c];
        else if (o < 128) v = Wk[(o - 64) * C_ + c];
        else              v = Wv[(o - 128) * C_ + c];
        Wcat[idx] = f2fp8(v);
    }
    if (idx < NO_) {
        float v = (idx < 64) ? bq[idx] : ((idx < 128) ? bk[idx - 64] : bv[idx - 128]);
        bcat[idx] = v;
    }
}

// ------------------------------------------------- K1: x[B,C,H,W] -> xT[b][w][h][c] fp8
__global__ __launch_bounds__(256) void k_transpose_x(const float* __restrict__ x, u8* __restrict__ xT) {
    __shared__ float tile[64][65];
    const int b  = blockIdx.x >> 7;
    const int h  = blockIdx.x & 127;
    const int c0 = (blockIdx.y >> 1) * 64;
    const int w0 = (blockIdx.y & 1) * 64;
    const int t = threadIdx.x, r = t >> 4, seg = t & 15;
    const float* xp = x + (size_t)b * C_ * H_ * W_ + (size_t)h * W_;
#pragma unroll
    for (int rr = 0; rr < 4; ++rr) {
        const int c = rr * 16 + r;
        float4 v = *(const float4*)(xp + (size_t)(c0 + c) * (H_ * W_) + w0 + seg * 4);
        tile[c][seg * 4 + 0] = v.x; tile[c][seg * 4 + 1] = v.y;
        tile[c][seg * 4 + 2] = v.z; tile[c][seg * 4 + 3] = v.w;
    }
    __syncthreads();
#pragma unroll
    for (int rr = 0; rr < 4; ++rr) {
        const int w = rr * 16 + r;
        const unsigned lo = f2fp8x2(tile[seg * 4 + 0][w], tile[seg * 4 + 1][w]);
        const unsigned hi = f2fp8x2(tile[seg * 4 + 2][w], tile[seg * 4 + 3][w]);
        *(unsigned*)(xT + ((size_t)((b * W_ + w0 + w) * H_ + h)) * C_ + c0 + seg * 4)
            = (lo & 0xFFFFu) | (hi << 16);
    }
}

// ------------------------------------------------- K2: MX-fp8 GEMM, B de-staged to registers
// BM=128, BN=128, BK=128, 4 waves (2M x 2N), mfma_scale_f32_16x16x128_f8f6f4 (scales = 1.0).
// A: LDS dbuf 2 x 16 KB (gld16, swizzled); B (0.33 MB, L2-resident): direct global->VGPR,
// double-buffered reg sets, prefetched one step ahead. Per K-step: vmcnt(0) -> s_barrier ->
// 8 ds_read (A frags) -> STAGE_A(T+1) + LOADB(T+1) -> 16 MFMA. Epilogue T[128][144] reuses smem.
// Swizzle (A only): seg_phys = seg ^ (row&7); gld16 dest linear, source pre-swizzled.
__global__ __launch_bounds__(256, 2) void k_gemm(const u8* __restrict__ A, const u8* __restrict__ Wc,
                                                 const float* __restrict__ bias, u8* __restrict__ Call,
                                                 u8* __restrict__ vt) {
    __shared__ __align__(16) u8 smem[32768];   // A dbuf 2x16KB; epilogue T[128][144] (18.4 KB) reuses it
    const int t = threadIdx.x;
    const int lane = t & 63;
    const int wave = t >> 6;
    const int wr = wave >> 1;          // M half (64 rows)
    const int wc = wave & 1;           // N half (64 cols)
    const int lr = lane & 15;
    const int q4 = lane >> 4;          // 0..3: lane's k-window = q4*32 .. +32 within BK slice

    // bijective XCD-chunk swizzle: 2560 = 8 XCDs x 320; n fastest within a panel
    const int bid = blockIdx.x;
    const int wg = (bid & 7) * 320 + (bid >> 3);
    const int panel = wg / 5;          // = bw (0..511)
    const int n = wg - panel * 5;
    const int r0 = panel * 128;
    const int n0 = n * 128;

    // A staging: thread t covers row srow (32 rows/round), phys seg t&7; source pre-swizzled
    const int srow = t >> 3;           // 0..31
    const int slog = (t & 7) ^ (srow & 7);
    const u8* gA = A + (size_t)(r0 + srow) * C_ + slog * 16;

#define STAGE_A(KT) do {                                                 \
        u8* S_ = smem + ((KT) & 1) * 16384;                              \
        const int k0_ = (KT) * 128;                                      \
        gld16(gA + k0_,                    S_ + t * 16);                 \
        gld16(gA + (size_t)32 * C_ + k0_,  S_ + 4096  + t * 16);         \
        gld16(gA + (size_t)64 * C_ + k0_,  S_ + 8192  + t * 16);         \
        gld16(gA + (size_t)96 * C_ + k0_,  S_ + 12288 + t * 16);         \
    } while (0)

    // B direct: lane's row = n0 + wc*64 + ni*16 + lr; bytes q4*32 and q4*32+16 of k-slice T
    const u8* gBw = Wc + (size_t)(n0 + wc * 64 + lr) * C_ + q4 * 32;
#define LOADB(DST, KT) do {                                              \
        _Pragma("unroll") for (int ni = 0; ni < 4; ++ni) {               \
            DST[ni][0] = *(const int4*)(gBw + (size_t)ni * 16 * C_ + (KT) * 128);       \
            DST[ni][1] = *(const int4*)(gBw + (size_t)ni * 16 * C_ + (KT) * 128 + 16);  \
        }                                                                \
    } while (0)

    int4 B0[4][2], B1[4][2];
    f32x4 acc[4][4] = {};
    STAGE_A(0);
    LOADB(B0, 0);

#define KSTEP(T, BCUR, BNXT) do {                                        \
        asm volatile("s_waitcnt vmcnt(0)" ::: "memory");                 \
        __builtin_amdgcn_s_barrier();                                    \
        const u8* Ab = smem + ((T) & 1) * 16384;                         \
        v8i fa[4];                                                       \
        _Pragma("unroll") for (int mi = 0; mi < 4; ++mi) {               \
            const int rr = wr * 64 + mi * 16 + lr;                       \
            int4 lo = *(const int4*)&Ab[rr * 128 + (((2 * q4 + 0) ^ (rr & 7)) * 16)]; \
            int4 hi = *(const int4*)&Ab[rr * 128 + (((2 * q4 + 1) ^ (rr & 7)) * 16)]; \
            v8i f; f[0] = lo.x; f[1] = lo.y; f[2] = lo.z; f[3] = lo.w;   \
                   f[4] = hi.x; f[5] = hi.y; f[6] = hi.z; f[7] = hi.w;   \
            fa[mi] = f;                                                  \
        }                                                                \
        if ((T) < 3) { STAGE_A((T) + 1); LOADB(BNXT, (T) + 1); }         \
        __builtin_amdgcn_s_setprio(1);                                   \
        _Pragma("unroll") for (int mi = 0; mi < 4; ++mi)                 \
        _Pragma("unroll") for (int ni = 0; ni < 4; ++ni) {               \
            v8i fb; fb[0] = BCUR[ni][0].x; fb[1] = BCUR[ni][0].y;        \
                    fb[2] = BCUR[ni][0].z; fb[3] = BCUR[ni][0].w;        \
                    fb[4] = BCUR[ni][1].x; fb[5] = BCUR[ni][1].y;        \
                    fb[6] = BCUR[ni][1].z; fb[7] = BCUR[ni][1].w;        \
            acc[mi][ni] = __builtin_amdgcn_mfma_scale_f32_16x16x128_f8f6f4( \
                fa[mi], fb, acc[mi][ni],                                 \
                0, 0, 0, 0x7F7F7F7Fu, 0, 0x7F7F7F7Fu);                   \
        }                                                                \
        __builtin_amdgcn_s_setprio(0);                                   \
    } while (0)

    KSTEP(0, B0, B1);
    KSTEP(1, B1, B0);
    KSTEP(2, B0, B1);
    KSTEP(3, B1, B0);
#undef KSTEP
#undef LOADB
#undef STAGE_A
    __syncthreads();                                       // all A-buf ds_reads retired before T reuse

    // C/D mapping (shape-determined): col = lane&15, row = (lane>>4)*4 + j
    if (n == 0) {
        // Q/K: Call[row][o] fp8, o = wc*64 + ni*16 + lr (0..127)
#pragma unroll
        for (int ni = 0; ni < 4; ++ni) {
            const int o = wc * 64 + ni * 16 + lr;
            const float bz = bias[o];
#pragma unroll
            for (int mi = 0; mi < 4; ++mi)
#pragma unroll
                for (int j = 0; j < 4; ++j) {
                    const int rg = r0 + wr * 64 + mi * 16 + q4 * 4 + j;
                    Call[(size_t)rg * 128 + o] = f2fp8(acc[mi][ni][j] + bz);
                }
        }
    } else {
        // V: transpose through T[128][144] fp8 -> vt[(bw*512 + cg)*128 + h]
        u8* Tt = smem;
#pragma unroll
        for (int ni = 0; ni < 4; ++ni) {
            const int c_loc = wc * 64 + ni * 16 + lr;        // 0..127
            const float bz = bias[n0 + c_loc];
#pragma unroll
            for (int mi = 0; mi < 4; ++mi) {
                const int h = wr * 64 + mi * 16 + q4 * 4;    // 4 consecutive h (j=0..3)
                unsigned p = f2fp8x2(acc[mi][ni][0] + bz, acc[mi][ni][1] + bz) & 0xFFFFu;
                p |= f2fp8x2(acc[mi][ni][2] + bz, acc[mi][ni][3] + bz) << 16;
                *(unsigned*)&Tt[c_loc * 144 + h] = p;
            }
        }
        __syncthreads();
        {
            const int c_loc = t >> 1;                        // 0..127
            const int half  = t & 1;                         // h half (64)
            const int cg = (n - 1) * 128 + c_loc;            // V channel 0..511
            u8* dst = vt + ((size_t)panel * 512 + cg) * 128 + half * 64;
            const u8* src = &Tt[c_loc * 144 + half * 64];
#pragma unroll
            for (int k = 0; k < 4; ++k)
                *(int4*)&dst[k * 16] = *(const int4*)&src[k * 16];
        }
    }
}

// ------------------------------------------------- K4: per-(b,w) axial attention (fp8 in/out)
__global__ __launch_bounds__(256) void k_attn(const u8* __restrict__ Call, const u8* __restrict__ vt,
                                              u8* __restrict__ outws) {
    __shared__ __align__(16) float E[128][132];
    __shared__ float Rinv[128];
    const int bw = blockIdx.x;
    const int t = threadIdx.x;
    const int lane = t & 63;
    const int wr = t >> 7;
    const int wc = (t >> 6) & 1;
    const int lr = lane & 15, lk = (lane >> 4) * 8;
    const size_t rowbase = (size_t)bw * 128;

    // ---- energy = Q K^T (K-dim = 64 channels); Call row = 128 B fp8
    f32x4 e[4][4] = {};
#pragma unroll
    for (int kk = 0; kk < 2; ++kk) {
        long fq[4], fk[4];
#pragma unroll
        for (int mi = 0; mi < 4; ++mi)
            fq[mi] = *(const long*)&Call[(rowbase + wr * 64 + mi * 16 + lr) * 128 + kk * 32 + lk];
#pragma unroll
        for (int ni = 0; ni < 4; ++ni)
            fk[ni] = *(const long*)&Call[(rowbase + wc * 64 + ni * 16 + lr) * 128 + 64 + kk * 32 + lk];
#pragma unroll
        for (int mi = 0; mi < 4; ++mi)
#pragma unroll
            for (int ni = 0; ni < 4; ++ni)
                e[mi][ni] = __builtin_amdgcn_mfma_f32_16x16x32_fp8_fp8(fq[mi], fk[ni], e[mi][ni], 0, 0, 0);
    }
#pragma unroll
    for (int mi = 0; mi < 4; ++mi)
#pragma unroll
        for (int ni = 0; ni < 4; ++ni)
#pragma unroll
            for (int j = 0; j < 4; ++j)
                E[wr * 64 + mi * 16 + (lane >> 4) * 4 + j][wc * 64 + ni * 16 + lr] = e[mi][ni][j];
    __syncthreads();

    // ---- softmax over g (rows h), exp in place, 2 threads per row
    {
        const int h = t >> 1, hf = (t & 1) * 64;
        float m = -1e30f;
        for (int i = 0; i < 64; ++i) m = fmaxf(m, E[h][hf + i]);
        m = fmaxf(m, __shfl_xor(m, 1));
        float s = 0.f;
        for (int i = 0; i < 64; ++i) {
            float p = __expf(E[h][hf + i] - m);
            E[h][hf + i] = p;
            s += p;
        }
        s += __shfl_xor(s, 1);
        if ((t & 1) == 0) Rinv[h] = 1.0f / s;
    }
    __syncthreads();

    float rv[4][4];
#pragma unroll
    for (int mi = 0; mi < 4; ++mi)
#pragma unroll
        for (int j = 0; j < 4; ++j)
            rv[mi][j] = Rinv[wr * 64 + mi * 16 + (lane >> 4) * 4 + j];

    // ---- P rows -> fp8 fragments ONCE
    long pa[4][4];
#pragma unroll
    for (int kk = 0; kk < 4; ++kk)
#pragma unroll
        for (int mi = 0; mi < 4; ++mi) {
            const float* ep = &E[wr * 64 + mi * 16 + lr][kk * 32 + lk];
            float4 v0 = *(const float4*)ep;
            float4 v1 = *(const float4*)(ep + 4);
            unsigned lo = (unsigned)__builtin_amdgcn_cvt_pk_fp8_f32(v0.x, v0.y, 0, false);
            lo = (unsigned)__builtin_amdgcn_cvt_pk_fp8_f32(v0.z, v0.w, (int)lo, true);
            unsigned hi = (unsigned)__builtin_amdgcn_cvt_pk_fp8_f32(v1.x, v1.y, 0, false);
            hi = (unsigned)__builtin_amdgcn_cvt_pk_fp8_f32(v1.z, v1.w, (int)hi, true);
            pa[kk][mi] = (long)lo | ((long)hi << 32);
        }

    // ---- out = P V (vt rows = 128 B fp8)
    for (int cc = 0; cc < 4; ++cc) {
        f32x4 acc[4][4] = {};
#pragma unroll
        for (int kk = 0; kk < 4; ++kk) {
            long fb[4];
#pragma unroll
            for (int ni = 0; ni < 4; ++ni)
                fb[ni] = *(const long*)&vt[((size_t)bw * 512 + cc * 128 + wc * 64 + ni * 16 + lr) * 128 + kk * 32 + lk];
#pragma unroll
            for (int mi = 0; mi < 4; ++mi)
#pragma unroll
                for (int ni = 0; ni < 4; ++ni)
                    acc[mi][ni] = __builtin_amdgcn_mfma_f32_16x16x32_fp8_fp8(pa[kk][mi], fb[ni], acc[mi][ni], 0, 0, 0);
        }
#pragma unroll
        for (int ni = 0; ni < 4; ++ni) {
            const int c = cc * 128 + wc * 64 + ni * 16 + lr;
#pragma unroll
            for (int mi = 0; mi < 4; ++mi)
#pragma unroll
                for (int j = 0; j < 4; ++j) {
                    const int hh = wr * 64 + mi * 16 + (lane >> 4) * 4 + j;
                    outws[(rowbase + hh) * 512 + c] = f2fp8(acc[mi][ni][j] * rv[mi][j]);
                }
        }
    }
}

// ------------------------------------------------- K5: out = gamma*out_ws^T + x (fp8 outws)
__global__ __launch_bounds__(256) void k_merge(const u8* __restrict__ outws, const float* __restrict__ x,
                                               const float* __restrict__ gamma, float* __restrict__ out) {
    __shared__ float tile[64][65];
    const int b  = blockIdx.x >> 7;
    const int h  = blockIdx.x & 127;
    const int c0 = (blockIdx.y >> 1) * 64;
    const int w0 = (blockIdx.y & 1) * 64;
    const float g = gamma[0];
    const int t = threadIdx.x, r = t >> 4, seg = t & 15;
#pragma unroll
    for (int rr = 0; rr < 4; ++rr) {
        const int w = rr * 16 + r;
        unsigned v = *(const unsigned*)(outws + ((size_t)((b * W_ + w0 + w) * H_) + h) * C_ + c0 + seg * 4);
        tile[w][seg * 4 + 0] = fp82f(v & 0xFFu);
        tile[w][seg * 4 + 1] = fp82f((v >> 8) & 0xFFu);
        tile[w][seg * 4 + 2] = fp82f((v >> 16) & 0xFFu);
        tile[w][seg * 4 + 3] = fp82f(v >> 24);
    }
    __syncthreads();
#pragma unroll
    for (int rr = 0; rr < 4; ++rr) {
        const int c = rr * 16 + r;
        const size_t base = ((size_t)(b * C_ + c0 + c) * H_ + h) * W_ + w0 + seg * 4;
        float4 xv = *(const float4*)(x + base);
        float4 o;
        o.x = g * tile[seg * 4 + 0][c] + xv.x;
        o.y = g * tile[seg * 4 + 1][c] + xv.y;
        o.z = g * tile[seg * 4 + 2][c] + xv.z;
        o.w = g * tile[seg * 4 + 3][c] + xv.w;
        *(float4*)(out + base) = o;
    }
}

extern "C" void kernel_launch(void* const* d_in, const int* in_sizes, int n_in,
                              void* d_out, int out_size, void* d_ws, size_t ws_size,
                              hipStream_t stream) {
    const float* x     = (const float*)d_in[0];
    const float* Wq    = (const float*)d_in[1];
    const float* bq    = (const float*)d_in[2];
    const float* Wk    = (const float*)d_in[3];
    const float* bk    = (const float*)d_in[4];
    const float* Wv    = (const float*)d_in[5];
    const float* bv    = (const float*)d_in[6];
    const float* gamma = (const float*)d_in[7];

    char* ws = (char*)d_ws;
    u8*    Wcat  = (u8*)ws;                                    //   0.33 MB (fp8)
    float* bcat  = (float*)(ws + 655360);                      //   2.5 KB
    u8*    xT    = (u8*)(ws + (1u << 20));                     //  33.5 MB (fp8)
    u8*    Call  = (u8*)(ws + (1u << 20) + 67108864);          //   8.4 MB (fp8 Q/K, stride 128)
    u8*    outws = (u8*)(ws + (1u << 20));                     //  xT region reused after k_gemm (33.5 MB fp8)
    u8*    vt    = (u8*)d_out;                                 //  first 33.5 MB of d_out; dead before k_merge writes

    k_convw<<<dim3((NO_ * C_ + 255) / 256), 256, 0, stream>>>(Wq, bq, Wk, bk, Wv, bv, Wcat, bcat);
    k_transpose_x<<<dim3(B_ * H_, 16), 256, 0, stream>>>(x, xT);
    k_gemm<<<dim3(2560), 256, 0, stream>>>(xT, Wcat, bcat, Call, vt);
    k_attn<<<dim3(B_ * W_), 256, 0, stream>>>(Call, vt, outws);
    k_merge<<<dim3(B_ * H_, 16), 256, 0, stream>>>(outws, x, gamma, (float*)d_out);
}

// Round 19
// 153.867 us; speedup vs baseline: 1.1349x; 1.1349x over previous
//
#include <hip/hip_runtime.h>
#include <hip/hip_bf16.h>

typedef float f32x4  __attribute__((ext_vector_type(4)));
typedef int   v8i    __attribute__((ext_vector_type(8)));
typedef unsigned short u16;
typedef unsigned char  u8;

#define B_ 4
#define C_ 512
#define H_ 128
#define W_ 128
#define NO_ 640   // 64 q + 64 k + 512 v output channels

__device__ __forceinline__ u16 f2bf(float f) {
    __hip_bfloat16 h = __float2bfloat16(f);
    union { __hip_bfloat16 h; u16 u; } cv; cv.h = h; return cv.u;
}
// fp8 e4m3 (OCP) pack: two floats -> low 2 bytes of result
__device__ __forceinline__ unsigned f2fp8x2(float a, float b) {
    return (unsigned)__builtin_amdgcn_cvt_pk_fp8_f32(a, b, 0, false);
}
__device__ __forceinline__ u8 f2fp8(float f) {
    return (u8)(f2fp8x2(f, 0.f) & 0xFF);
}
// branchless e4m3fn -> f32 decode (no builtin dependency)
__device__ __forceinline__ float fp82f(unsigned b) {
    const unsigned s = (b >> 7) & 1u, e = (b >> 3) & 15u, m = b & 7u;
    union { unsigned u; float f; } c;
    c.u = (s << 31) | ((e + 120u) << 23) | (m << 20);            // normal
    const float fs = (s ? -1.f : 1.f) * (float)m * 0.001953125f; // subnormal: m*2^-9
    return e ? c.f : fs;
}

// async global->LDS, 16B per lane; LDS dest must be wave_base + lane*16
__device__ __forceinline__ void gld16(const void* g, void* l) {
    __builtin_amdgcn_global_load_lds(
        (const __attribute__((address_space(1))) void*)g,
        (__attribute__((address_space(3))) void*)l, 16, 0, 0);
}

// ---------------------------------------------------------------- K0: weights -> fp8
__global__ __launch_bounds__(256) void k_convw(const float* __restrict__ Wq, const float* __restrict__ bq,
                                               const float* __restrict__ Wk, const float* __restrict__ bk,
                                               const float* __restrict__ Wv, const float* __restrict__ bv,
                                               u8* __restrict__ Wcat, float* __restrict__ bcat) {
    const int idx = blockIdx.x * 256 + threadIdx.x;
    if (idx < NO_ * C_) {
        const int o = idx >> 9, c = idx & 511;
        float v;
        if (o < 64)       v = Wq[o * C_ + c];
        else if (o < 128) v = Wk[(o - 64) * C_ + c];
        else              v = Wv[(o - 128) * C_ + c];
        Wcat[idx] = f2fp8(v);
    }
    if (idx < NO_) {
        float v = (idx < 64) ? bq[idx] : ((idx < 128) ? bk[idx - 64] : bv[idx - 128]);
        bcat[idx] = v;
    }
}

// ------------------------------------------------- K1: x[B,C,H,W] -> xT[b][w][h][c] fp8
__global__ __launch_bounds__(256) void k_transpose_x(const float* __restrict__ x, u8* __restrict__ xT) {
    __shared__ float tile[64][65];
    const int b  = blockIdx.x >> 7;
    const int h  = blockIdx.x & 127;
    const int c0 = (blockIdx.y >> 1) * 64;
    const int w0 = (blockIdx.y & 1) * 64;
    const int t = threadIdx.x, r = t >> 4, seg = t & 15;
    const float* xp = x + (size_t)b * C_ * H_ * W_ + (size_t)h * W_;
#pragma unroll
    for (int rr = 0; rr < 4; ++rr) {
        const int c = rr * 16 + r;
        float4 v = *(const float4*)(xp + (size_t)(c0 + c) * (H_ * W_) + w0 + seg * 4);
        tile[c][seg * 4 + 0] = v.x; tile[c][seg * 4 + 1] = v.y;
        tile[c][seg * 4 + 2] = v.z; tile[c][seg * 4 + 3] = v.w;
    }
    __syncthreads();
#pragma unroll
    for (int rr = 0; rr < 4; ++rr) {
        const int w = rr * 16 + r;
        const unsigned lo = f2fp8x2(tile[seg * 4 + 0][w], tile[seg * 4 + 1][w]);
        const unsigned hi = f2fp8x2(tile[seg * 4 + 2][w], tile[seg * 4 + 3][w]);
        *(unsigned*)(xT + ((size_t)((b * W_ + w0 + w) * H_ + h)) * C_ + c0 + seg * 4)
            = (lo & 0xFFFFu) | (hi << 16);
    }
}

// ------------------------------------------------- K2: MX-fp8 GEMM, BK=128 dbuf, unit scales
// BM=128, BN=128, BK=128, 4 waves (2M x 2N), mfma_scale_f32_16x16x128_f8f6f4 (scales = 1.0).
// LDS: dbuf 2 x (A 16KB + B 16KB) = 64 KB -> 2 blocks/CU; epilogue T[128][144] aliases buf0.
// Per K-step: vmcnt(0) -> s_barrier -> 16 ds_read_b128 -> STAGE(T+1, other buf) -> 16 MFMA/wave.
// LDS row = 128 B = 8 x 16B segs; swizzle seg_phys = seg ^ (row&7);
// gld16 dest linear, global source pre-swizzled ((i*32+srow)&7 invariant = srow&7).
__global__ __launch_bounds__(256, 2) void k_gemm(const u8* __restrict__ A, const u8* __restrict__ Wc,
                                                 const float* __restrict__ bias, u8* __restrict__ Call,
                                                 u8* __restrict__ vt) {
    __shared__ __align__(16) u8 smem[65536];   // 64 KB dbuf; epilogue T[128][144] aliases first 18.4 KB
    const int t = threadIdx.x;
    const int lane = t & 63;
    const int wave = t >> 6;
    const int wr = wave >> 1;          // M half (64 rows)
    const int wc = wave & 1;           // N half (64 cols)
    const int lr = lane & 15;
    const int q4 = lane >> 4;          // 0..3: lane's k-window = q4*32 .. +32 within BK slice

    // bijective XCD-chunk swizzle: 2560 = 8 XCDs x 320; n fastest within a panel
    const int bid = blockIdx.x;
    const int wg = (bid & 7) * 320 + (bid >> 3);
    const int panel = wg / 5;          // = bw (0..511)
    const int n = wg - panel * 5;
    const int r0 = panel * 128;
    const int n0 = n * 128;

    // staging: thread t covers row srow (32 rows/round), phys seg t&7; source pre-swizzled
    const int srow = t >> 3;           // 0..31
    const int slog = (t & 7) ^ (srow & 7);
    const u8* gA = A  + (size_t)(r0 + srow) * C_ + slog * 16;
    const u8* gB = Wc + (size_t)(n0 + srow) * C_ + slog * 16;

#define STAGE(KT) do {                                                   \
        u8* S_ = smem + ((KT) & 1) * 32768;                              \
        const int k0_ = (KT) * 128;                                      \
        gld16(gA + k0_,                    S_ + t * 16);                 \
        gld16(gA + (size_t)32 * C_ + k0_,  S_ + 4096  + t * 16);         \
        gld16(gA + (size_t)64 * C_ + k0_,  S_ + 8192  + t * 16);         \
        gld16(gA + (size_t)96 * C_ + k0_,  S_ + 12288 + t * 16);         \
        gld16(gB + k0_,                    S_ + 16384 + t * 16);         \
        gld16(gB + (size_t)32 * C_ + k0_,  S_ + 20480 + t * 16);         \
        gld16(gB + (size_t)64 * C_ + k0_,  S_ + 24576 + t * 16);         \
        gld16(gB + (size_t)96 * C_ + k0_,  S_ + 28672 + t * 16);         \
    } while (0)

    f32x4 acc[4][4] = {};
    STAGE(0);

#pragma unroll
    for (int T = 0; T < 4; ++T) {
        asm volatile("s_waitcnt vmcnt(0)" ::: "memory");   // STAGE(T) landed (issued one phase ago)
        __builtin_amdgcn_s_barrier();
        const u8* Ab = smem + (T & 1) * 32768;
        const u8* Bb = Ab + 16384;
        v8i fa[4], fb[4];
#pragma unroll
        for (int mi = 0; mi < 4; ++mi) {
            const int rr = wr * 64 + mi * 16 + lr;
            int4 lo = *(const int4*)&Ab[rr * 128 + (((2 * q4 + 0) ^ (rr & 7)) * 16)];
            int4 hi = *(const int4*)&Ab[rr * 128 + (((2 * q4 + 1) ^ (rr & 7)) * 16)];
            v8i f; f[0] = lo.x; f[1] = lo.y; f[2] = lo.z; f[3] = lo.w;
                   f[4] = hi.x; f[5] = hi.y; f[6] = hi.z; f[7] = hi.w;
            fa[mi] = f;
        }
#pragma unroll
        for (int ni = 0; ni < 4; ++ni) {
            const int rr = wc * 64 + ni * 16 + lr;
            int4 lo = *(const int4*)&Bb[rr * 128 + (((2 * q4 + 0) ^ (rr & 7)) * 16)];
            int4 hi = *(const int4*)&Bb[rr * 128 + (((2 * q4 + 1) ^ (rr & 7)) * 16)];
            v8i f; f[0] = lo.x; f[1] = lo.y; f[2] = lo.z; f[3] = lo.w;
                   f[4] = hi.x; f[5] = hi.y; f[6] = hi.z; f[7] = hi.w;
            fb[ni] = f;
        }
        if (T < 3) STAGE(T + 1);                           // other buf; last read at T-1, guarded by barrier(T)
        __builtin_amdgcn_s_setprio(1);
#pragma unroll
        for (int mi = 0; mi < 4; ++mi)
#pragma unroll
            for (int ni = 0; ni < 4; ++ni)
                acc[mi][ni] = __builtin_amdgcn_mfma_scale_f32_16x16x128_f8f6f4(
                    fa[mi], fb[ni], acc[mi][ni],
                    0, 0,                    // cbsz = fp8 e4m3, blgp = fp8 e4m3
                    0, 0x7F7F7F7Fu,          // opsel_a, scale_a (all E8M0 = 127 -> 1.0)
                    0, 0x7F7F7F7Fu);         // opsel_b, scale_b
        __builtin_amdgcn_s_setprio(0);
    }
#undef STAGE
    __syncthreads();                                       // all buf reads done before T reuse

    // C/D mapping (shape-determined): col = lane&15, row = (lane>>4)*4 + j
    if (n == 0) {
        // Q/K: Call[row][o] fp8, o = wc*64 + ni*16 + lr (0..127)
#pragma unroll
        for (int ni = 0; ni < 4; ++ni) {
            const int o = wc * 64 + ni * 16 + lr;
            const float bz = bias[o];
#pragma unroll
            for (int mi = 0; mi < 4; ++mi)
#pragma unroll
                for (int j = 0; j < 4; ++j) {
                    const int rg = r0 + wr * 64 + mi * 16 + q4 * 4 + j;
                    Call[(size_t)rg * 128 + o] = f2fp8(acc[mi][ni][j] + bz);
                }
        }
    } else {
        // V: transpose through T[128][144] fp8 -> vt[(bw*512 + cg)*128 + h]
        u8* Tt = smem;
#pragma unroll
        for (int ni = 0; ni < 4; ++ni) {
            const int c_loc = wc * 64 + ni * 16 + lr;        // 0..127
            const float bz = bias[n0 + c_loc];
#pragma unroll
            for (int mi = 0; mi < 4; ++mi) {
                const int h = wr * 64 + mi * 16 + q4 * 4;    // 4 consecutive h (j=0..3)
                unsigned p = f2fp8x2(acc[mi][ni][0] + bz, acc[mi][ni][1] + bz) & 0xFFFFu;
                p |= f2fp8x2(acc[mi][ni][2] + bz, acc[mi][ni][3] + bz) << 16;
                *(unsigned*)&Tt[c_loc * 144 + h] = p;
            }
        }
        __syncthreads();
        {
            const int c_loc = t >> 1;                        // 0..127
            const int half  = t & 1;                         // h half (64)
            const int cg = (n - 1) * 128 + c_loc;            // V channel 0..511
            u8* dst = vt + ((size_t)panel * 512 + cg) * 128 + half * 64;
            const u8* src = &Tt[c_loc * 144 + half * 64];
#pragma unroll
            for (int k = 0; k < 4; ++k)
                *(int4*)&dst[k * 16] = *(const int4*)&src[k * 16];
        }
    }
}

// ------------------------------------------------- K4: per-(b,w) axial attention (fp8 in/out)
__global__ __launch_bounds__(256) void k_attn(const u8* __restrict__ Call, const u8* __restrict__ vt,
                                              u8* __restrict__ outws) {
    __shared__ __align__(16) float E[128][132];
    __shared__ float Rinv[128];
    const int bw = blockIdx.x;
    const int t = threadIdx.x;
    const int lane = t & 63;
    const int wr = t >> 7;
    const int wc = (t >> 6) & 1;
    const int lr = lane & 15, lk = (lane >> 4) * 8;
    const size_t rowbase = (size_t)bw * 128;

    // ---- energy = Q K^T (K-dim = 64 channels); Call row = 128 B fp8
    f32x4 e[4][4] = {};
#pragma unroll
    for (int kk = 0; kk < 2; ++kk) {
        long fq[4], fk[4];
#pragma unroll
        for (int mi = 0; mi < 4; ++mi)
            fq[mi] = *(const long*)&Call[(rowbase + wr * 64 + mi * 16 + lr) * 128 + kk * 32 + lk];
#pragma unroll
        for (int ni = 0; ni < 4; ++ni)
            fk[ni] = *(const long*)&Call[(rowbase + wc * 64 + ni * 16 + lr) * 128 + 64 + kk * 32 + lk];
#pragma unroll
        for (int mi = 0; mi < 4; ++mi)
#pragma unroll
            for (int ni = 0; ni < 4; ++ni)
                e[mi][ni] = __builtin_amdgcn_mfma_f32_16x16x32_fp8_fp8(fq[mi], fk[ni], e[mi][ni], 0, 0, 0);
    }
#pragma unroll
    for (int mi = 0; mi < 4; ++mi)
#pragma unroll
        for (int ni = 0; ni < 4; ++ni)
#pragma unroll
            for (int j = 0; j < 4; ++j)
                E[wr * 64 + mi * 16 + (lane >> 4) * 4 + j][wc * 64 + ni * 16 + lr] = e[mi][ni][j];
    __syncthreads();

    // ---- softmax over g (rows h), exp in place, 2 threads per row
    {
        const int h = t >> 1, hf = (t & 1) * 64;
        float m = -1e30f;
        for (int i = 0; i < 64; ++i) m = fmaxf(m, E[h][hf + i]);
        m = fmaxf(m, __shfl_xor(m, 1));
        float s = 0.f;
        for (int i = 0; i < 64; ++i) {
            float p = __expf(E[h][hf + i] - m);
            E[h][hf + i] = p;
            s += p;
        }
        s += __shfl_xor(s, 1);
        if ((t & 1) == 0) Rinv[h] = 1.0f / s;
    }
    __syncthreads();

    float rv[4][4];
#pragma unroll
    for (int mi = 0; mi < 4; ++mi)
#pragma unroll
        for (int j = 0; j < 4; ++j)
            rv[mi][j] = Rinv[wr * 64 + mi * 16 + (lane >> 4) * 4 + j];

    // ---- P rows -> fp8 fragments ONCE
    long pa[4][4];
#pragma unroll
    for (int kk = 0; kk < 4; ++kk)
#pragma unroll
        for (int mi = 0; mi < 4; ++mi) {
            const float* ep = &E[wr * 64 + mi * 16 + lr][kk * 32 + lk];
            float4 v0 = *(const float4*)ep;
            float4 v1 = *(const float4*)(ep + 4);
            unsigned lo = (unsigned)__builtin_amdgcn_cvt_pk_fp8_f32(v0.x, v0.y, 0, false);
            lo = (unsigned)__builtin_amdgcn_cvt_pk_fp8_f32(v0.z, v0.w, (int)lo, true);
            unsigned hi = (unsigned)__builtin_amdgcn_cvt_pk_fp8_f32(v1.x, v1.y, 0, false);
            hi = (unsigned)__builtin_amdgcn_cvt_pk_fp8_f32(v1.z, v1.w, (int)hi, true);
            pa[kk][mi] = (long)lo | ((long)hi << 32);
        }

    // ---- out = P V (vt rows = 128 B fp8)
    for (int cc = 0; cc < 4; ++cc) {
        f32x4 acc[4][4] = {};
#pragma unroll
        for (int kk = 0; kk < 4; ++kk) {
            long fb[4];
#pragma unroll
            for (int ni = 0; ni < 4; ++ni)
                fb[ni] = *(const long*)&vt[((size_t)bw * 512 + cc * 128 + wc * 64 + ni * 16 + lr) * 128 + kk * 32 + lk];
#pragma unroll
            for (int mi = 0; mi < 4; ++mi)
#pragma unroll
                for (int ni = 0; ni < 4; ++ni)
                    acc[mi][ni] = __builtin_amdgcn_mfma_f32_16x16x32_fp8_fp8(pa[kk][mi], fb[ni], acc[mi][ni], 0, 0, 0);
        }
#pragma unroll
        for (int ni = 0; ni < 4; ++ni) {
            const int c = cc * 128 + wc * 64 + ni * 16 + lr;
#pragma unroll
            for (int mi = 0; mi < 4; ++mi)
#pragma unroll
                for (int j = 0; j < 4; ++j) {
                    const int hh = wr * 64 + mi * 16 + (lane >> 4) * 4 + j;
                    outws[(rowbase + hh) * 512 + c] = f2fp8(acc[mi][ni][j] * rv[mi][j]);
                }
        }
    }
}

// ------------------------------------------------- K5: out = gamma*out_ws^T + x (fp8 outws)
__global__ __launch_bounds__(256) void k_merge(const u8* __restrict__ outws, const float* __restrict__ x,
                                               const float* __restrict__ gamma, float* __restrict__ out) {
    __shared__ float tile[64][65];
    const int b  = blockIdx.x >> 7;
    const int h  = blockIdx.x & 127;
    const int c0 = (blockIdx.y >> 1) * 64;
    const int w0 = (blockIdx.y & 1) * 64;
    const float g = gamma[0];
    const int t = threadIdx.x, r = t >> 4, seg = t & 15;
#pragma unroll
    for (int rr = 0; rr < 4; ++rr) {
        const int w = rr * 16 + r;
        unsigned v = *(const unsigned*)(outws + ((size_t)((b * W_ + w0 + w) * H_) + h) * C_ + c0 + seg * 4);
        tile[w][seg * 4 + 0] = fp82f(v & 0xFFu);
        tile[w][seg * 4 + 1] = fp82f((v >> 8) & 0xFFu);
        tile[w][seg * 4 + 2] = fp82f((v >> 16) & 0xFFu);
        tile[w][seg * 4 + 3] = fp82f(v >> 24);
    }
    __syncthreads();
#pragma unroll
    for (int rr = 0; rr < 4; ++rr) {
        const int c = rr * 16 + r;
        const size_t base = ((size_t)(b * C_ + c0 + c) * H_ + h) * W_ + w0 + seg * 4;
        float4 xv = *(const float4*)(x + base);
        float4 o;
        o.x = g * tile[seg * 4 + 0][c] + xv.x;
        o.y = g * tile[seg * 4 + 1][c] + xv.y;
        o.z = g * tile[seg * 4 + 2][c] + xv.z;
        o.w = g * tile[seg * 4 + 3][c] + xv.w;
        *(float4*)(out + base) = o;
    }
}

extern "C" void kernel_launch(void* const* d_in, const int* in_sizes, int n_in,
                              void* d_out, int out_size, void* d_ws, size_t ws_size,
                              hipStream_t stream) {
    const float* x     = (const float*)d_in[0];
    const float* Wq    = (const float*)d_in[1];
    const float* bq    = (const float*)d_in[2];
    const float* Wk    = (const float*)d_in[3];
    const float* bk    = (const float*)d_in[4];
    const float* Wv    = (const float*)d_in[5];
    const float* bv    = (const float*)d_in[6];
    const float* gamma = (const float*)d_in[7];

    char* ws = (char*)d_ws;
    u8*    Wcat  = (u8*)ws;                                    //   0.33 MB (fp8)
    float* bcat  = (float*)(ws + 655360);                      //   2.5 KB
    u8*    xT    = (u8*)(ws + (1u << 20));                     //  33.5 MB (fp8)
    u8*    Call  = (u8*)(ws + (1u << 20) + 67108864);          //   8.4 MB (fp8 Q/K, stride 128)
    u8*    outws = (u8*)(ws + (1u << 20));                     //  xT region reused after k_gemm (33.5 MB fp8)
    u8*    vt    = (u8*)d_out;                                 //  first 33.5 MB of d_out; dead before k_merge writes

    k_convw<<<dim3((NO_ * C_ + 255) / 256), 256, 0, stream>>>(Wq, bq, Wk, bk, Wv, bv, Wcat, bcat);
    k_transpose_x<<<dim3(B_ * H_, 16), 256, 0, stream>>>(x, xT);
    k_gemm<<<dim3(2560), 256, 0, stream>>>(xT, Wcat, bcat, Call, vt);
    k_attn<<<dim3(B_ * W_), 256, 0, stream>>>(Call, vt, outws);
    k_merge<<<dim3(B_ * H_, 16), 256, 0, stream>>>(outws, x, gamma, (float*)d_out);
}